// Round 6
// baseline (411.065 us; speedup 1.0000x reference)
//
#include <hip/hip_runtime.h>
#include <stdint.h>

typedef unsigned short u16;
typedef unsigned int   u32;
typedef __attribute__((ext_vector_type(8))) __bf16 bf16x8;
typedef __attribute__((ext_vector_type(4))) float  f32x4;

#define MFMA_16x16x32_BF16(a, b, c) __builtin_amdgcn_mfma_f32_16x16x32_bf16((a), (b), (c), 0, 0, 0)

__device__ __forceinline__ u16 f2b(float f) {
    u32 u = __builtin_bit_cast(u32, f);
    u32 r = (u + 0x7FFFu + ((u >> 16) & 1u)) >> 16;
    return (u16)r;
}
__device__ __forceinline__ float b2f(u16 h) {
    u32 u = ((u32)h) << 16;
    return __builtin_bit_cast(float, u);
}

// async 16B/lane global->LDS; LDS destination is wave-uniform base + lane*16
__device__ __forceinline__ void gload_lds16(const void* g, void* l) {
    __builtin_amdgcn_global_load_lds(
        (const __attribute__((address_space(1))) u32*)g,
        (__attribute__((address_space(3))) u32*)l,
        16, 0, 0);
}

// ---------------------------------------------------------------------------
// Stage 1: fp32 -> bf16 casts for x, w_qkv, w_proj (grid-stride, float4 lanes)
// ---------------------------------------------------------------------------
__global__ __launch_bounds__(256) void cast3(const float* __restrict__ x,
                                             const float* __restrict__ wq,
                                             const float* __restrict__ wp,
                                             u16* __restrict__ xb,
                                             u16* __restrict__ wqb,
                                             u16* __restrict__ wpb) {
    const int n1 = 8388608, n2 = 12582912, n3 = 4194304;
    const int total4 = (n1 + n2 + n3) / 4;
    for (int i = blockIdx.x * blockDim.x + threadIdx.x; i < total4;
         i += gridDim.x * blockDim.x) {
        int e = i * 4;
        const float* src; u16* dst; int off;
        if (e < n1)            { src = x;  dst = xb;  off = e; }
        else if (e < n1 + n2)  { src = wq; dst = wqb; off = e - n1; }
        else                   { src = wp; dst = wpb; off = e - n1 - n2; }
        float4 v = *(const float4*)(src + off);
        ushort4 o;
        o.x = f2b(v.x); o.y = f2b(v.y); o.z = f2b(v.z); o.w = f2b(v.w);
        *(ushort4*)(dst + off) = o;
    }
}

// ---------------------------------------------------------------------------
// Stage 2/6: C[M,N] = A[M,K] * Bt[N,K]^T (bf16 in, fp32 acc), 128x128 tile,
// BK=64, 256 threads, XOR-swizzled LDS. Keeper structure (873 TF); the 256^2
// 4-phase ports (rounds 1-2) both landed at 717 TF -> line closed.
// ---------------------------------------------------------------------------
template <int OUT_BF16>
__global__ __launch_bounds__(256) void gemm_bt(const u16* __restrict__ A,
                                               const u16* __restrict__ Bt,
                                               void* __restrict__ Cout,
                                               int M, int N, int K) {
    __shared__ u16 Al[128 * 64];
    __shared__ u16 Bl[128 * 64];
    const int tid  = threadIdx.x;
    const int w    = tid >> 6;
    const int lane = tid & 63;
    const int quad = lane >> 4;
    const int l16  = lane & 15;
    const int m0 = blockIdx.y * 128;
    const int n0 = blockIdx.x * 128;
    const int wm = (w >> 1) * 64;
    const int wn = (w & 1) * 64;

    f32x4 acc[4][4];
#pragma unroll
    for (int i = 0; i < 4; i++) {
#pragma unroll
        for (int j = 0; j < 4; j++) acc[i][j] = (f32x4){0.f, 0.f, 0.f, 0.f};
    }

    const int srow = tid >> 3;
    const int scol = ((tid & 7) ^ (srow & 7)) * 8;
    const u16* Abase = A + (size_t)(m0 + srow) * K + scol;
    const u16* Bbase = Bt + (size_t)(n0 + srow) * K + scol;
    char* AlB = (char*)Al + w * 1024;
    char* BlB = (char*)Bl + w * 1024;
    const int fx = (l16 & 7);

    for (int k0 = 0; k0 < K; k0 += 64) {
        __syncthreads();
#pragma unroll
        for (int i = 0; i < 4; i++) {
            gload_lds16(Abase + (size_t)i * 32 * K + k0, AlB + i * 4096);
            gload_lds16(Bbase + (size_t)i * 32 * K + k0, BlB + i * 4096);
        }
        __syncthreads();
#pragma unroll
        for (int ks = 0; ks < 2; ks++) {
            const int cb = ((ks * 4 + quad) ^ fx) * 8;
            bf16x8 Af[4];
#pragma unroll
            for (int mi = 0; mi < 4; mi++)
                Af[mi] = *(const bf16x8*)&Al[(wm + mi * 16 + l16) * 64 + cb];
#pragma unroll
            for (int ni = 0; ni < 4; ni++) {
                bf16x8 Bf = *(const bf16x8*)&Bl[(wn + ni * 16 + l16) * 64 + cb];
#pragma unroll
                for (int mi = 0; mi < 4; mi++)
                    acc[mi][ni] = MFMA_16x16x32_BF16(Af[mi], Bf, acc[mi][ni]);
            }
        }
    }

    const int row0 = m0 + wm + quad * 4;
    const int col0 = n0 + wn + l16;
#pragma unroll
    for (int mi = 0; mi < 4; mi++) {
#pragma unroll
        for (int r = 0; r < 4; r++) {
            size_t rowb = (size_t)(row0 + mi * 16 + r) * N;
#pragma unroll
            for (int ni = 0; ni < 4; ni++) {
                float v = acc[mi][ni][r];
                if (OUT_BF16) ((u16*)Cout)[rowb + col0 + ni * 16] = f2b(v);
                else          ((float*)Cout)[rowb + col0 + ni * 16] = v;
            }
        }
    }
}

// ---------------------------------------------------------------------------
// Stage 3: RoPE on q,k. Only 64 unique angles per (b,t) block: build a shared
// cos/sin table once (64 sincosf instead of 2048 -> 32x less trans/VALU).
// ---------------------------------------------------------------------------
__global__ __launch_bounds__(256) void rope_qk(const u16* __restrict__ qkv,
                                               u16* __restrict__ Q,
                                               u16* __restrict__ K) {
    __shared__ float cs[64], sn[64];
    const int bt = blockIdx.x;          // 0..4095
    const int b = bt >> 11, t = bt & 2047;
    const u16* row = qkv + (size_t)bt * 6144;
    const int tid = threadIdx.x;

    if (tid < 64) {
        float inv = __expf(-0.14391156f * (float)tid);   // 10000^(-tid/64)
        float s, c;
        sincosf((float)t * inv, &s, &c);
        sn[tid] = s; cs[tid] = c;
    }
    __syncthreads();

#pragma unroll
    for (int it = 0; it < 8; it++) {
        int p   = it * 256 + tid;
        int qk  = p >> 10;          // 0=q, 1=k (wave-uniform per it)
        int rem = p & 1023;
        int h   = rem >> 6;
        int i   = rem & 63;
        float x1 = b2f(row[qk * 2048 + h * 128 + i]);
        float x2 = b2f(row[qk * 2048 + h * 128 + i + 64]);
        float s = sn[i], c = cs[i];
        float o1 = x1 * c - x2 * s;
        float o2 = x2 * c + x1 * s;
        u16* dst = (qk ? K : Q) + ((size_t)((b * 16 + h) * 2048 + t)) * 128;
        dst[i]      = f2b(o1);
        dst[i + 64] = f2b(o2);
    }
}

// ---------------------------------------------------------------------------
// Stage 4: V transpose: qkv v-slice -> VT[B,H,Dh,T]; grid (32 tc, 32 bh)
// ---------------------------------------------------------------------------
__global__ __launch_bounds__(256) void vtrans(const u16* __restrict__ qkv,
                                              u16* __restrict__ VT) {
    __shared__ u16 S[64 * 136];         // [t][d], padded stride 136
    const int tc = blockIdx.x;
    const int bh = blockIdx.y;
    const int b = bh >> 4, h = bh & 15;
    const int tid = threadIdx.x;

#pragma unroll
    for (int i = 0; i < 4; i++) {
        int idx = i * 256 + tid;
        int t  = idx >> 4;
        int d8 = (idx & 15) * 8;
        uint4 v = *(const uint4*)(qkv + ((size_t)(b * 2048 + tc * 64 + t)) * 6144
                                      + 4096 + h * 128 + d8);
        *(uint4*)&S[t * 136 + d8] = v;
    }
    __syncthreads();
#pragma unroll
    for (int i = 0; i < 4; i++) {
        int idx = i * 256 + tid;
        int d  = idx >> 3;
        int t8 = (idx & 7) * 8;
        u16 tmp[8];
#pragma unroll
        for (int j = 0; j < 8; j++) tmp[j] = S[(t8 + j) * 136 + d];
        *(uint4*)(VT + ((size_t)(bh * 128 + d)) * 2048 + tc * 64 + t8) = *(uint4*)tmp;
    }
}

// ---------------------------------------------------------------------------
// Stage 5: causal flash attention v6: 2 waves x 32 q-rows (was 4 x 16).
// All waves of a block read IDENTICAL K/V fragments (addresses independent
// of w), so halving the wave count at constant block q-tile (64) halves the
// per-block LDS read traffic (the dominant cost: ~46us of the kernel) while
// keeping total MFMA constant -- each K/V fragment now feeds 2 MFMAs (qi=0,1).
// 128 thr/block, grid (16 pairs, 32 bh) = 512 blocks = 2/CU (LDS 75.3KB x2).
// 1 wave/SIMD -> launch_bounds(128,1) lifts VGPR cap to 512 (no spill risk).
// ---------------------------------------------------------------------------
__global__ __launch_bounds__(128, 1) void attn(const u16* __restrict__ Q,
                                               const u16* __restrict__ Kg,
                                               const u16* __restrict__ VTg,
                                               u16* __restrict__ O) {
    __shared__ u16 Kl[2][64 * 128];     // [buf][key][d], XOR-swizzled
    __shared__ u16 Vt[2][128 * 64];     // [buf][d][key], XOR-swizzled
    __shared__ u16 Pl[2 * 32 * 76];     // per-wave P[q 32][key 64], stride 76

    const int tid  = threadIdx.x;
    const int w    = tid >> 6;          // 0..1
    const int lane = tid & 63;
    const int quad = lane >> 4;
    const int l16  = lane & 15;
    const int pair = blockIdx.x;        // 0..15
    const int bh   = blockIdx.y;        // 0..31
    const int b = bh >> 4, h = bh & 15;
    const size_t base = (size_t)bh * 2048 * 128;
    const u16* Qb  = Q + base;
    const u16* Kb  = Kg + base;
    const u16* VTb = VTg + base;        // [128 d][2048 t]
    u16* Plw = Pl + w * 32 * 76;
    const float scale = 0.08838834764831845f;   // 1/sqrt(128)

    // staging (128 thr): K tile 64x256B -> 8 issues of 8 rows;
    // V tile 128x128B -> 8 issues of 16 rows. XOR swizzle via source col.
    const int krow = tid >> 4;                          // 0..7
    const int kcol = ((tid & 15) ^ (krow & 7)) * 8;     // u16 units
    const int vrow = tid >> 3;                          // 0..15
    const int vcol = ((tid & 7) ^ (vrow & 7)) * 8;
    const int fx   = (l16 & 7);                         // fragment-read swizzle

    for (int s = 0; s < 2; s++) {
        const int qt   = s ? (31 - pair) : pair;
        const int q0   = qt * 64;
        const int row0 = q0 + w * 32;   // this wave's first q row

        // Q fragments (B operand of S^T MFMA), 2 q-subtiles of 16
        bf16x8 Qf[4][2];
#pragma unroll
        for (int kk = 0; kk < 4; kk++)
#pragma unroll
            for (int qi = 0; qi < 2; qi++)
                Qf[kk][qi] = *(const bf16x8*)
                    &Qb[(size_t)(row0 + qi * 16 + l16) * 128 + kk * 32 + quad * 8];

        f32x4 Oacc[8][2];
#pragma unroll
        for (int ni = 0; ni < 8; ni++)
#pragma unroll
            for (int qi = 0; qi < 2; qi++) Oacc[ni][qi] = (f32x4){0.f, 0.f, 0.f, 0.f};
        float m[2]    = {-1e30f, -1e30f};
        float lsum[2] = {0.f, 0.f};

        const int nkt = qt + 1;

        __syncthreads();    // protect buf0 from the previous s-iteration
        {
            const u16* ksrc = Kb + (size_t)krow * 128 + kcol;
            char* kdst = (char*)Kl[0] + w * 1024;
            const u16* vsrc = VTb + (size_t)vrow * 2048 + vcol;
            char* vdst = (char*)Vt[0] + w * 1024;
#pragma unroll
            for (int i = 0; i < 8; i++) {
                gload_lds16(ksrc + (size_t)i * 1024, kdst + i * 2048);
                gload_lds16(vsrc + (size_t)i * 16 * 2048, vdst + i * 2048);
            }
        }

        for (int kt = 0; kt < nkt; kt++) {
            const int kt0 = kt * 64;
            const int cur = kt & 1;
            __syncthreads();    // drains async loads + syncs block

            if (kt + 1 < nkt) {
                const int kt1 = kt0 + 64;
                const u16* ksrc = Kb + (size_t)(kt1 + krow) * 128 + kcol;
                char* kdst = (char*)Kl[cur ^ 1] + w * 1024;
                const u16* vsrc = VTb + (size_t)vrow * 2048 + kt1 + vcol;
                char* vdst = (char*)Vt[cur ^ 1] + w * 1024;
#pragma unroll
                for (int i = 0; i < 8; i++) {
                    gload_lds16(ksrc + (size_t)i * 1024, kdst + i * 2048);
                    gload_lds16(vsrc + (size_t)i * 16 * 2048, vdst + i * 2048);
                }
            }

            const u16* Klc = Kl[cur];
            const u16* Vtc = Vt[cur];

            // S^T = K Q^T: D[key][q], each Kf feeds both q-subtiles
            f32x4 ST[4][2];
#pragma unroll
            for (int mi = 0; mi < 4; mi++)
#pragma unroll
                for (int qi = 0; qi < 2; qi++) ST[mi][qi] = (f32x4){0.f, 0.f, 0.f, 0.f};
#pragma unroll
            for (int kk = 0; kk < 4; kk++) {
                const int cb = ((kk * 4 + quad) ^ fx) * 8;
#pragma unroll
                for (int mi = 0; mi < 4; mi++) {
                    bf16x8 Kf = *(const bf16x8*)&Klc[(mi * 16 + l16) * 128 + cb];
                    ST[mi][0] = MFMA_16x16x32_BF16(Kf, Qf[kk][0], ST[mi][0]);
                    ST[mi][1] = MFMA_16x16x32_BF16(Kf, Qf[kk][1], ST[mi][1]);
                }
            }

            // scale + causal mask + per-lane tile max (two q states per lane)
            float tmax[2] = {-1e30f, -1e30f};
#pragma unroll
            for (int qi = 0; qi < 2; qi++) {
                const bool needs_mask = (kt0 + 63) > (row0 + qi * 16);
                const int qg = row0 + qi * 16 + l16;
#pragma unroll
                for (int mi = 0; mi < 4; mi++) {
#pragma unroll
                    for (int r = 0; r < 4; r++) {
                        float sv = ST[mi][qi][r] * scale;
                        if (needs_mask) {
                            int kg = kt0 + mi * 16 + quad * 4 + r;
                            sv = (kg > qg) ? -1e30f : sv;
                        }
                        ST[mi][qi][r] = sv;
                        tmax[qi] = fmaxf(tmax[qi], sv);
                    }
                }
                tmax[qi] = fmaxf(tmax[qi], __shfl_xor(tmax[qi], 16));
                tmax[qi] = fmaxf(tmax[qi], __shfl_xor(tmax[qi], 32));
            }

            // T13 defer-max: rescale only when some row's max grew by > 8
            if (__any((tmax[0] > m[0] + 8.0f) || (tmax[1] > m[1] + 8.0f))) {
#pragma unroll
                for (int qi = 0; qi < 2; qi++) {
                    float mnew  = fmaxf(m[qi], tmax[qi]);
                    float alpha = __expf(m[qi] - mnew);
                    m[qi] = mnew;
                    lsum[qi] *= alpha;
                    float aRow[4];
#pragma unroll
                    for (int r = 0; r < 4; r++) aRow[r] = __shfl(alpha, quad * 4 + r);
#pragma unroll
                    for (int ni = 0; ni < 8; ni++)
#pragma unroll
                        for (int r = 0; r < 4; r++) Oacc[ni][qi][r] *= aRow[r];
                }
            }

#pragma unroll
            for (int qi = 0; qi < 2; qi++) {
                float ts = 0.f;
#pragma unroll
                for (int mi = 0; mi < 4; mi++) {
#pragma unroll
                    for (int r = 0; r < 4; r++) {
                        float p = __expf(ST[mi][qi][r] - m[qi]);
                        ST[mi][qi][r] = p;
                        ts += p;
                    }
                }
                lsum[qi] += ts;
#pragma unroll
                for (int mi = 0; mi < 4; mi++) {
                    ushort4 pk;
                    pk.x = f2b(ST[mi][qi][0]); pk.y = f2b(ST[mi][qi][1]);
                    pk.z = f2b(ST[mi][qi][2]); pk.w = f2b(ST[mi][qi][3]);
                    *(ushort4*)&Plw[(qi * 16 + l16) * 76 + mi * 16 + quad * 4] = pk;
                }
            }

            // O += P V : each Vf feeds both q-subtiles
            bf16x8 Pf[2][2];
#pragma unroll
            for (int kk = 0; kk < 2; kk++)
#pragma unroll
                for (int qi = 0; qi < 2; qi++)
                    Pf[kk][qi] = *(const bf16x8*)
                        &Plw[(qi * 16 + l16) * 76 + kk * 32 + quad * 8];
#pragma unroll
            for (int kk = 0; kk < 2; kk++) {
                const int cb = ((kk * 4 + quad) ^ fx) * 8;
#pragma unroll
                for (int ni = 0; ni < 8; ni++) {
                    bf16x8 Vf = *(const bf16x8*)&Vtc[(ni * 16 + l16) * 64 + cb];
                    Oacc[ni][0] = MFMA_16x16x32_BF16(Pf[kk][0], Vf, Oacc[ni][0]);
                    Oacc[ni][1] = MFMA_16x16x32_BF16(Pf[kk][1], Vf, Oacc[ni][1]);
                }
            }
        }

        // final normalization per q-subtile
#pragma unroll
        for (int qi = 0; qi < 2; qi++) {
            float l2 = lsum[qi];
            l2 += __shfl_xor(l2, 16);
            l2 += __shfl_xor(l2, 32);
            float inv = 1.0f / l2;
            float iRow[4];
#pragma unroll
            for (int r = 0; r < 4; r++) iRow[r] = __shfl(inv, quad * 4 + r);
#pragma unroll
            for (int r = 0; r < 4; r++) {
                int t = row0 + qi * 16 + quad * 4 + r;
                size_t rowb = ((size_t)(b * 2048 + t)) * 2048 + (size_t)(h * 128);
#pragma unroll
                for (int ni = 0; ni < 8; ni++)
                    O[rowb + ni * 16 + l16] = f2b(Oacc[ni][qi][r] * iRow[r]);
            }
        }
    }
}

// ---------------------------------------------------------------------------
extern "C" void kernel_launch(void* const* d_in, const int* in_sizes, int n_in,
                              void* d_out, int out_size, void* d_ws, size_t ws_size,
                              hipStream_t stream) {
    const float* x  = (const float*)d_in[0];
    const float* wq = (const float*)d_in[1];
    const float* wp = (const float*)d_in[2];

    char* ws = (char*)d_ws;
    u16* xb   = (u16*)(ws + 0);            // 16,777,216 B
    u16* wqb  = (u16*)(ws + 16777216);     // 25,165,824 B
    u16* wpb  = (u16*)(ws + 41943040);     //  8,388,608 B
    u16* qkvb = (u16*)(ws + 50331648);     // 50,331,648 B
    u16* Qr   = (u16*)(ws + 100663296);    // 16,777,216 B
    u16* Kr   = (u16*)(ws + 117440512);    // 16,777,216 B
    u16* VTt  = (u16*)(ws + 134217728);    // 16,777,216 B (V^T, [B,H,Dh,T])
    u16* Ob   = (u16*)(ws + 50331648);     // overlays qkvb (dead after rope/vtrans)
    if (ws_size < 150994944) return;

    cast3<<<2048, 256, 0, stream>>>(x, wq, wp, xb, wqb, wpb);
    gemm_bt<1><<<dim3(48, 32), 256, 0, stream>>>(xb, wqb, qkvb, 4096, 6144, 2048);
    rope_qk<<<4096, 256, 0, stream>>>(qkvb, Qr, Kr);
    vtrans<<<dim3(32, 32), 256, 0, stream>>>(qkvb, VTt);
    attn<<<dim3(16, 32), 128, 0, stream>>>(Qr, Kr, VTt, Ob);
    gemm_bt<0><<<dim3(16, 32), 256, 0, stream>>>(Ob, wpb, (float*)d_out, 4096, 2048, 2048);
}